// Round 8
// baseline (494.685 us; speedup 1.0000x reference)
//
#include <hip/hip_runtime.h>
#include <stdint.h>

// Problem constants (fixed by reference: L=1024, B=8, D=2048)
#define L_SEQ 1024
#define BATCH 8
#define DIM   2048
#define GM    8192   // L*B
#define GN    6144   // 3*D
#define GK    2048   // D
#define SCALE_X 1.7320508075688772f  // sqrt(1 + 2*exp(0))

// GEMM geometry: 256x256 tile, 8 waves (2M x 4N), k-ring of 4 slices of 32
#define BM 256
#define BN 256
#define BKC 32

// U4 scan layout: [b][dch=d>>6][l][dl*4 + slot], slot = {u0,u1,u2,x}, shorts.
// Per-(b,dch) region = 1024 * 256 shorts = 512 KB, sequential in l.
#define U4_BSTRIDE ((size_t)32 * 1024 * 256)   // shorts per b increment

using bf16x8  = __attribute__((ext_vector_type(8))) __bf16;
using floatx4 = __attribute__((ext_vector_type(4))) float;

__device__ __forceinline__ unsigned short f2bf(float f) {
  unsigned u = __float_as_uint(f);
  u += 0x7FFFu + ((u >> 16) & 1u);   // round-to-nearest-even
  return (unsigned short)(u >> 16);
}
__device__ __forceinline__ float sigmoidf_fast(float z) {
  return __builtin_amdgcn_rcpf(1.0f + __expf(-z));
}
__device__ __forceinline__ void async16(const unsigned short* g, unsigned short* l) {
  __builtin_amdgcn_global_load_lds(
      (__attribute__((address_space(1))) unsigned int*)g,
      (__attribute__((address_space(3))) unsigned int*)l,
      16, 0, 0);
}

// ------------- fused prep: transpose-cast W -> Bt  +  cast x -> A + U4.x --------
// Blocks [0, 3072): 64x64 transpose tiles (n-tile = blk%96, k-tile = blk/96).
//   Reads W via float4; writes Bt rows as 16B ushort8 chunks (full-line groups).
// Blocks [3072, 7168): grid-stride cast of x -> A_bf (gemm input, contiguous 8B)
//   and -> U4 x-slots (scan input; 4x 2B scatter at stride 8B; partial lines
//   merge with gemm's u-writes in L3).
// W col n = 3d+j -> j==0: Bt row d (u0 plane); j>0: Bt row DIM + 2d + (j-1).
__global__ __launch_bounds__(256) void prep_kernel(const float4* __restrict__ xin,
                                                   unsigned short* __restrict__ Aout,
                                                   const float* __restrict__ W,
                                                   unsigned short* __restrict__ Bt,
                                                   unsigned short* __restrict__ U4) {
  __shared__ float tile[64][65];
  const int blk = blockIdx.x;
  if (blk < 3072) {
    const int tx = threadIdx.x & 15, ty = threadIdx.x >> 4;
    const int n0 = (blk % 96) * 64;
    const int k0 = (blk / 96) * 64;
#pragma unroll
    for (int p = 0; p < 4; ++p) {
      const float4 v = *(const float4*)&W[(size_t)(k0 + ty + 16 * p) * GN + n0 + tx * 4];
      float* t = &tile[ty + 16 * p][tx * 4];
      t[0] = v.x; t[1] = v.y; t[2] = v.z; t[3] = v.w;
    }
    __syncthreads();
#pragma unroll
    for (int p = 0; p < 2; ++p) {
      const int jl = (threadIdx.x >> 3) + 32 * p;          // 0..63 n-local
      const int n = n0 + jl;
      const int dq = n / 3, j3 = n - 3 * dq;
      const int np = (j3 == 0) ? dq : (DIM + 2 * dq + (j3 - 1));
      const int klb = (threadIdx.x & 7) * 8;               // 0..56 k-local
      union { unsigned short s[8]; uint4 q; } o;
#pragma unroll
      for (int kk = 0; kk < 8; ++kk) o.s[kk] = f2bf(tile[klb + kk][jl]);
      *(uint4*)&Bt[(size_t)np * GK + k0 + klb] = o.q;
    }
  } else {
    const int n4 = (GM * GK) / 4;
    for (int i = (blk - 3072) * 256 + threadIdx.x; i < n4; i += 4096 * 256) {
      float4 v = xin[i];
      union { unsigned short s[4]; unsigned long long ll; } o;
      o.s[0] = f2bf(v.x); o.s[1] = f2bf(v.y); o.s[2] = f2bf(v.z); o.s[3] = f2bf(v.w);
      *(unsigned long long*)&Aout[(size_t)i * 4] = o.ll;
      const int f4 = i * 4;                    // flat (gm,d); d..d+3 in one row
      const int gm = f4 >> 11, d = f4 & (DIM - 1);
      const int l = gm >> 3, b = gm & 7;
      unsigned short* xb = U4 + ((size_t)(b * 32 + (d >> 6)) * 1024 + l) * 256
                              + (d & 63) * 4 + 3;
      xb[0] = o.s[0]; xb[4] = o.s[1]; xb[8] = o.s[2]; xb[12] = o.s[3];
    }
  }
}

// ---------------- GEMM: U4 <- A(GM x GK) * Bt(GN x GK)^T, bf16 out --------------
// Round-4 structure verbatim (best measured: 197us, MfmaUtil 46.7, conflicts 0):
// 256x256 tile, 8 waves (2M x 4N), per-wave 128x64 = 8x4 reps of 16x16x32 MFMA.
// LDS = ring of 4 k-slices (k=32) per matrix: 128 KB, 1 blk/CU.
// Per chunk c: WAITV(8) ; BAR0 ; R0(8 ds_read) + stageA(c+3) ; BAR1 ; lgkm0 ;
// 16 MFMA ; BAR2 ; R1(4 ds_read) + stageB(c+3) ; BAR3 ; lgkm0 ; 16 MFMA.
// WAITV(8) waits only chunk c's loads (issued 3 chunks earlier -> free).
// Only the EPILOGUE differs: writes go to the U4 scan layout (index permutation
// only; same 4x32B-segment store coalescing; partial lines merge in L3).
// LDS swizzle: 16B slot S(row,s) = (row>>1)*8 + (((row&1)*4+s)^((row>>1)&7));
// read-side XOR + inverse-permuted global source (LDS dest lane-linear).
// XCD-rectangle swizzle: 768 = 8 XCD x 3 rounds x (4y x 8x).

#define WAITV(N) asm volatile("s_waitcnt vmcnt(" #N ")" ::: "memory")
#define LGKM0 asm volatile("s_waitcnt lgkmcnt(0)" ::: "memory"); \
              __builtin_amdgcn_sched_barrier(0)

#define CHUNK(cexpr, SL, DOSTAGE)                                             \
  {                                                                           \
    __builtin_amdgcn_s_barrier();  /* BAR0 */                                 \
    __builtin_amdgcn_sched_barrier(0);                                        \
    const int c_ = (cexpr);                                                   \
    const char* aB_ = AsB + (SL) * 16384;                                     \
    const char* bB_ = BsB + (SL) * 16384;                                     \
    bf16x8 bF[4], aF[4];                                                      \
    _Pragma("unroll") for (int nt = 0; nt < 4; ++nt)                          \
        bF[nt] = *(const bf16x8*)(bB_ + SB0 + nt * 1024);                     \
    _Pragma("unroll") for (int mt = 0; mt < 4; ++mt)                          \
        aF[mt] = *(const bf16x8*)(aB_ + SA0 + mt * 1024);                     \
    if (DOSTAGE) {                                                            \
      unsigned short* ad_ = (unsigned short*)(AsL + ((c_ + 3) & 3) * 16384);  \
      const int ko_ = (c_ + 3) * BKC;                                         \
      async16(aG0 + ko_, ad_ + L0 * 8);                                       \
      async16(aG1 + ko_, ad_ + L1 * 8);                                       \
    }                                                                         \
    __builtin_amdgcn_sched_barrier(0);                                        \
    __builtin_amdgcn_s_barrier();  /* BAR1: read-burst | MFMA-burst fence */  \
    LGKM0;                                                                    \
    __builtin_amdgcn_s_setprio(1);                                            \
    _Pragma("unroll") for (int mt = 0; mt < 4; ++mt)                          \
      _Pragma("unroll") for (int nt = 0; nt < 4; ++nt)                        \
        acc[mt][nt] = __builtin_amdgcn_mfma_f32_16x16x32_bf16(                \
            aF[mt], bF[nt], acc[mt][nt], 0, 0, 0);                            \
    __builtin_amdgcn_s_setprio(0);                                            \
    __builtin_amdgcn_sched_barrier(0);                                        \
    __builtin_amdgcn_s_barrier();  /* BAR2 */                                 \
    _Pragma("unroll") for (int mt = 0; mt < 4; ++mt)                          \
        aF[mt] = *(const bf16x8*)(aB_ + SA0 + 4096 + mt * 1024);              \
    if (DOSTAGE) {                                                            \
      unsigned short* bd_ = (unsigned short*)(BsL + ((c_ + 3) & 3) * 16384);  \
      const int ko_ = (c_ + 3) * BKC;                                         \
      async16(bG0 + ko_, bd_ + L0 * 8);                                       \
      async16(bG1 + ko_, bd_ + L1 * 8);                                       \
    }                                                                         \
    __builtin_amdgcn_sched_barrier(0);                                        \
    __builtin_amdgcn_s_barrier();  /* BAR3 */                                 \
    LGKM0;                                                                    \
    __builtin_amdgcn_s_setprio(1);                                            \
    _Pragma("unroll") for (int mt = 0; mt < 4; ++mt)                          \
      _Pragma("unroll") for (int nt = 0; nt < 4; ++nt)                        \
        acc[mt + 4][nt] = __builtin_amdgcn_mfma_f32_16x16x32_bf16(            \
            aF[mt], bF[nt], acc[mt + 4][nt], 0, 0, 0);                        \
    __builtin_amdgcn_s_setprio(0);                                            \
    __builtin_amdgcn_sched_barrier(0);                                        \
  }

__global__ __launch_bounds__(512, 2) void gemm_kernel(const unsigned short* __restrict__ A,
                                                      const unsigned short* __restrict__ Bt,
                                                      unsigned short* __restrict__ U4) {
  __shared__ alignas(16) unsigned short As[4][BM * BKC];  // 64 KB
  __shared__ alignas(16) unsigned short Bs[4][BN * BKC];  // 64 KB
  const int tid  = threadIdx.x;
  const int wave = tid >> 6, lane = tid & 63;
  const int quad = lane >> 4, lrow = lane & 15;
  const int wm = (wave >> 2) * 128;  // 2 M-waves
  const int wn = (wave & 3) * 64;    // 4 N-waves

  // XCD-rectangle swizzle: 768 blocks = 8 XCD x 3 rounds x 32 slots (4y x 8x)
  const int f    = blockIdx.y * (GN / BN) + blockIdx.x;
  const int xcd  = f & 7;
  const int slot = f >> 3;
  const int rnd  = slot >> 5;        // 0..2
  const int ss   = slot & 31;        // 0..31
  const int mBase = (4 * xcd + (ss & 3)) * BM;   // y-tile 0..31
  const int nBase = (8 * rnd + (ss >> 2)) * BN;  // x-tile 0..23

  floatx4 acc[8][4] = {};

  // staging: thread owns 16B slots L0=tid, L1=tid+512 of each slice (lane-linear
  // LDS dest). Invert swizzle to find the (row, k-slot) this slot must hold.
  const int L0 = tid, L1 = tid + 512;
  int r0, s0, r1, s1;
  { const int p = L0 >> 3, w = L0 & 7, v = w ^ (p & 7); r0 = 2 * p + (v >> 2); s0 = v & 3; }
  { const int p = L1 >> 3, w = L1 & 7, v = w ^ (p & 7); r1 = 2 * p + (v >> 2); s1 = v & 3; }
  const unsigned short* aG0 = A  + (size_t)(mBase + r0) * GK + s0 * 8;
  const unsigned short* aG1 = A  + (size_t)(mBase + r1) * GK + s1 * 8;
  const unsigned short* bG0 = Bt + (size_t)(nBase + r0) * GK + s0 * 8;
  const unsigned short* bG1 = Bt + (size_t)(nBase + r1) * GK + s1 * 8;

  // ds_read byte offsets within a slice (+16 rows = +1024 B)
  const int rA = wm + lrow;
  const int SA0 = (rA >> 1) * 128 + ((((rA & 1) * 4 + quad) ^ ((rA >> 1) & 7)) * 16);
  const int rB = wn + lrow;
  const int SB0 = (rB >> 1) * 128 + ((((rB & 1) * 4 + quad) ^ ((rB >> 1) & 7)) * 16);
  const char* AsB = (const char*)As;
  const char* BsB = (const char*)Bs;
  char* AsL = (char*)As;
  char* BsL = (char*)Bs;

  // prologue: stage chunks 0,1,2 (12 loads/thread in flight)
#pragma unroll
  for (int c = 0; c < 3; ++c) {
    unsigned short* ad = (unsigned short*)(AsL + c * 16384);
    unsigned short* bd = (unsigned short*)(BsL + c * 16384);
    async16(aG0 + c * BKC, ad + L0 * 8);
    async16(aG1 + c * BKC, ad + L1 * 8);
    async16(bG0 + c * BKC, bd + L0 * 8);
    async16(bG1 + c * BKC, bd + L1 * 8);
  }

  // main loop: chunks 0..59 (stage c+3), then peeled 60..63
#pragma unroll 1
  for (int cc = 0; cc < 15; ++cc) {
    const int cb = cc * 4;
#pragma unroll
    for (int j = 0; j < 4; ++j) {
      WAITV(8);
      CHUNK(cb + j, j, true);
    }
  }
  WAITV(8); CHUNK(60, 0, true);   // stages chunk 63
  WAITV(8); CHUNK(61, 1, false);
  WAITV(4); CHUNK(62, 2, false);
  WAITV(0); CHUNK(63, 3, false);

  // Epilogue -> U4 layout. C/D: col = lane&15 (N), row = quad*4 + reg (M).
  // gm is 4-aligned -> l = gm>>3 fixed across q; b = (gm&7) + q.
#pragma unroll
  for (int mt = 0; mt < 8; ++mt) {
    const int gm = mBase + wm + mt * 16 + quad * 4;
    const int l = gm >> 3;
    const int b0 = gm & 7;
#pragma unroll
    for (int nt = 0; nt < 4; ++nt) {
      const int gn = nBase + wn + nt * 16 + lrow;
      int d, j;
      if (gn < DIM) { d = gn; j = 0; }
      else { d = (gn - DIM) >> 1; j = 1 + ((gn - DIM) & 1); }
      unsigned short* base = U4 + ((size_t)(b0 * 32 + (d >> 6)) * 1024 + l) * 256
                                + (d & 63) * 4 + j;
#pragma unroll
      for (int q = 0; q < 4; ++q)
        base[(size_t)q * U4_BSTRIDE] = f2bf(acc[mt][nt][q]);
    }
  }
}

// ---------------- SRU scan over U4: ONE contiguous b64 stream per block ---------
// Block (b,dch) owns a private 512 KB region, walked sequentially in l:
// per step one ds-coalesced 512B wave-load (64 lanes x 8B = {u0,u1,u2,x}).
// Rotating raw-register prefetch depth 32 (32 outstanding vm loads <= 63 cap).
// Arithmetic identical to prior rounds -> bit-identical results.
__global__ __launch_bounds__(64) void sru_scan_u4(const unsigned long long* __restrict__ U4,
                                                  const float* __restrict__ c0,
                                                  const float* __restrict__ wc,
                                                  const float* __restrict__ bias,
                                                  float* __restrict__ out) {
  const int blk = blockIdx.x;        // b*32 + dch
  const int b = blk >> 5, dch = blk & 31;
  const int dl = threadIdx.x;
  const int d = dch * 64 + dl;
  const int e = b * DIM + d;
  const float vf = wc[d], vr = wc[DIM + d];
  const float bfv = bias[d], brv = bias[DIM + d];
  float c = c0[e];

  constexpr int PF = 32;
  constexpr int XS = BATCH * DIM;

  const unsigned long long* up = U4 + (size_t)blk * 1024 * 64 + dl;  // +64/step
  float* hp = out + (size_t)b * DIM + d;

  unsigned long long pv[PF];
#pragma unroll
  for (int j = 0; j < PF; ++j) pv[j] = up[(size_t)j * 64];
  const unsigned long long* uf = up + (size_t)PF * 64;

  for (int l0 = 0; l0 < L_SEQ; l0 += PF) {
#pragma unroll
    for (int j = 0; j < PF; ++j) {
      const unsigned long long v = pv[j];
      pv[j] = *uf; uf += 64;           // raw prefetch, consumed PF iters later
      const unsigned lo = (unsigned)v, hi = (unsigned)(v >> 32);
      const float a0 = __uint_as_float(lo << 16);
      const float u1 = __uint_as_float(lo & 0xFFFF0000u);
      const float u2 = __uint_as_float(hi << 16);
      const float ax = __uint_as_float(hi & 0xFFFF0000u) * SCALE_X;
      const float f = sigmoidf_fast(u1 + fmaf(vf, c, bfv));
      c = fmaf(c - a0, f, a0);
      const float rr = sigmoidf_fast(u2 + fmaf(vr, c, brv));
      *hp = fmaf(rr, c - ax, ax);
      hp += XS;
    }
  }
  out[(size_t)L_SEQ * XS + e] = c;
}

// --------------------------------- launcher ------------------------------------
extern "C" void kernel_launch(void* const* d_in, const int* in_sizes, int n_in,
                              void* d_out, int out_size, void* d_ws, size_t ws_size,
                              hipStream_t stream) {
  const float* x    = (const float*)d_in[0];
  const float* c0   = (const float*)d_in[1];
  const float* W    = (const float*)d_in[2];
  const float* wc   = (const float*)d_in[3];
  const float* bias = (const float*)d_in[4];
  float* out = (float*)d_out;

  char* ws = (char*)d_ws;
  // layout: A 33,554,432 | Bt 25,165,824 | U4 134,217,728 (+32K scan-overread pad)
  unsigned short* A_bf  = (unsigned short*)(ws);
  unsigned short* Bt_bf = (unsigned short*)(ws + 34078720);
  unsigned short* U4_s  = (unsigned short*)(ws + 59244544);

  prep_kernel<<<7168, 256, 0, stream>>>((const float4*)x, A_bf, W, Bt_bf, U4_s);
  gemm_kernel<<<dim3(GN / BN, GM / BM), 512, 0, stream>>>(A_bf, Bt_bf, U4_s);
  sru_scan_u4<<<256, 64, 0, stream>>>((const unsigned long long*)U4_s, c0, wc, bias, out);
}

// Round 9
// 426.944 us; speedup vs baseline: 1.1587x; 1.1587x over previous
//
#include <hip/hip_runtime.h>
#include <stdint.h>

// Problem constants (fixed by reference: L=1024, B=8, D=2048)
#define L_SEQ 1024
#define BATCH 8
#define DIM   2048
#define GM    8192   // L*B
#define GN    6144   // 3*D
#define GK    2048   // D
#define SCALE_X 1.7320508075688772f  // sqrt(1 + 2*exp(0))
#define SCAN_PF 16

// GEMM geometry: 256x256 tile, 8 waves (2M x 4N), k-ring of 4 slices of 32
#define BM 256
#define BN 256
#define BKC 32

using bf16x8  = __attribute__((ext_vector_type(8))) __bf16;
using floatx4 = __attribute__((ext_vector_type(4))) float;

__device__ __forceinline__ unsigned short f2bf(float f) {
  unsigned u = __float_as_uint(f);
  u += 0x7FFFu + ((u >> 16) & 1u);   // round-to-nearest-even
  return (unsigned short)(u >> 16);
}
__device__ __forceinline__ float sigmoidf_fast(float z) {
  return __builtin_amdgcn_rcpf(1.0f + __expf(-z));
}
__device__ __forceinline__ void async16(const unsigned short* g, unsigned short* l) {
  __builtin_amdgcn_global_load_lds(
      (__attribute__((address_space(1))) unsigned int*)g,
      (__attribute__((address_space(3))) unsigned int*)l,
      16, 0, 0);
}

// ------------- fused prep: transpose-cast W -> Bt  +  cast x -> A (bf16) --------
// Blocks [0, 3072): 64x64 transpose tiles (n-tile = blk%96, k-tile = blk/96).
//   Reads W via float4 (16B/lane); writes Bt rows as 8x 16B ushort8 chunks ->
//   each 8-thread group covers one full 128-B line (no partial-line RMW).
// Blocks [3072, 7168): grid-stride streaming cast of x.
// W col n = 3d+j -> j==0: Bt row d (u0 plane); j>0: Bt row DIM + 2d + (j-1).
__global__ __launch_bounds__(256) void prep_kernel(const float4* __restrict__ xin,
                                                   unsigned short* __restrict__ Aout,
                                                   const float* __restrict__ W,
                                                   unsigned short* __restrict__ Bt) {
  __shared__ float tile[64][65];
  const int blk = blockIdx.x;
  if (blk < 3072) {
    const int tx = threadIdx.x & 15, ty = threadIdx.x >> 4;
    const int n0 = (blk % 96) * 64;
    const int k0 = (blk / 96) * 64;
#pragma unroll
    for (int p = 0; p < 4; ++p) {
      const float4 v = *(const float4*)&W[(size_t)(k0 + ty + 16 * p) * GN + n0 + tx * 4];
      float* t = &tile[ty + 16 * p][tx * 4];
      t[0] = v.x; t[1] = v.y; t[2] = v.z; t[3] = v.w;
    }
    __syncthreads();
#pragma unroll
    for (int p = 0; p < 2; ++p) {
      const int jl = (threadIdx.x >> 3) + 32 * p;          // 0..63 n-local
      const int n = n0 + jl;
      const int dq = n / 3, j3 = n - 3 * dq;
      const int np = (j3 == 0) ? dq : (DIM + 2 * dq + (j3 - 1));
      const int klb = (threadIdx.x & 7) * 8;               // 0..56 k-local
      union { unsigned short s[8]; uint4 q; } o;
#pragma unroll
      for (int kk = 0; kk < 8; ++kk) o.s[kk] = f2bf(tile[klb + kk][jl]);
      *(uint4*)&Bt[(size_t)np * GK + k0 + klb] = o.q;
    }
  } else {
    const int n4 = (GM * GK) / 4;
    for (int i = (blk - 3072) * 256 + threadIdx.x; i < n4; i += 4096 * 256) {
      float4 v = xin[i];
      union { unsigned short s[4]; unsigned long long ll; } o;
      o.s[0] = f2bf(v.x); o.s[1] = f2bf(v.y); o.s[2] = f2bf(v.z); o.s[3] = f2bf(v.w);
      *(unsigned long long*)&Aout[(size_t)i * 4] = o.ll;
    }
  }
}

// ---------------- GEMM: U = A(GM x GK) * Bt(GN x GK)^T, bf16 out ----------------
// Round-4 structure verbatim (best measured: 197us, MfmaUtil 46.7, conflicts 0):
// 256x256 tile, 8 waves (2M x 4N), per-wave 128x64 = 8x4 reps of 16x16x32 MFMA.
// LDS = ring of 4 k-slices (k=32) per matrix: 128 KB, 1 blk/CU.
// Per chunk c: WAITV(8) ; BAR0 ; R0(8 ds_read) + stageA(c+3) ; BAR1 ; lgkm0 ;
// 16 MFMA ; BAR2 ; R1(4 ds_read) + stageB(c+3) ; BAR3 ; lgkm0 ; 16 MFMA.
// WAITV(8) waits only chunk c's loads (issued 3 chunks earlier -> free).
// LDS swizzle: 16B slot S(row,s) = (row>>1)*8 + (((row&1)*4+s)^((row>>1)&7));
// read-side XOR + inverse-permuted global source (LDS dest lane-linear).
// XCD-rectangle swizzle: 768 = 8 XCD x 3 rounds x (4y x 8x).

#define WAITV(N) asm volatile("s_waitcnt vmcnt(" #N ")" ::: "memory")
#define LGKM0 asm volatile("s_waitcnt lgkmcnt(0)" ::: "memory"); \
              __builtin_amdgcn_sched_barrier(0)

#define CHUNK(cexpr, SL, DOSTAGE)                                             \
  {                                                                           \
    __builtin_amdgcn_s_barrier();  /* BAR0 */                                 \
    __builtin_amdgcn_sched_barrier(0);                                        \
    const int c_ = (cexpr);                                                   \
    const char* aB_ = AsB + (SL) * 16384;                                     \
    const char* bB_ = BsB + (SL) * 16384;                                     \
    bf16x8 bF[4], aF[4];                                                      \
    _Pragma("unroll") for (int nt = 0; nt < 4; ++nt)                          \
        bF[nt] = *(const bf16x8*)(bB_ + SB0 + nt * 1024);                     \
    _Pragma("unroll") for (int mt = 0; mt < 4; ++mt)                          \
        aF[mt] = *(const bf16x8*)(aB_ + SA0 + mt * 1024);                     \
    if (DOSTAGE) {                                                            \
      unsigned short* ad_ = (unsigned short*)(AsL + ((c_ + 3) & 3) * 16384);  \
      const int ko_ = (c_ + 3) * BKC;                                         \
      async16(aG0 + ko_, ad_ + L0 * 8);                                       \
      async16(aG1 + ko_, ad_ + L1 * 8);                                       \
    }                                                                         \
    __builtin_amdgcn_sched_barrier(0);                                        \
    __builtin_amdgcn_s_barrier();  /* BAR1: read-burst | MFMA-burst fence */  \
    LGKM0;                                                                    \
    __builtin_amdgcn_s_setprio(1);                                            \
    _Pragma("unroll") for (int mt = 0; mt < 4; ++mt)                          \
      _Pragma("unroll") for (int nt = 0; nt < 4; ++nt)                        \
        acc[mt][nt] = __builtin_amdgcn_mfma_f32_16x16x32_bf16(                \
            aF[mt], bF[nt], acc[mt][nt], 0, 0, 0);                            \
    __builtin_amdgcn_s_setprio(0);                                            \
    __builtin_amdgcn_sched_barrier(0);                                        \
    __builtin_amdgcn_s_barrier();  /* BAR2 */                                 \
    _Pragma("unroll") for (int mt = 0; mt < 4; ++mt)                          \
        aF[mt] = *(const bf16x8*)(aB_ + SA0 + 4096 + mt * 1024);              \
    if (DOSTAGE) {                                                            \
      unsigned short* bd_ = (unsigned short*)(BsL + ((c_ + 3) & 3) * 16384);  \
      const int ko_ = (c_ + 3) * BKC;                                         \
      async16(bG0 + ko_, bd_ + L0 * 8);                                       \
      async16(bG1 + ko_, bd_ + L1 * 8);                                       \
    }                                                                         \
    __builtin_amdgcn_sched_barrier(0);                                        \
    __builtin_amdgcn_s_barrier();  /* BAR3 */                                 \
    LGKM0;                                                                    \
    __builtin_amdgcn_s_setprio(1);                                            \
    _Pragma("unroll") for (int mt = 0; mt < 4; ++mt)                          \
      _Pragma("unroll") for (int nt = 0; nt < 4; ++nt)                        \
        acc[mt + 4][nt] = __builtin_amdgcn_mfma_f32_16x16x32_bf16(            \
            aF[mt], bF[nt], acc[mt + 4][nt], 0, 0, 0);                        \
    __builtin_amdgcn_s_setprio(0);                                            \
    __builtin_amdgcn_sched_barrier(0);                                        \
  }

__global__ __launch_bounds__(512, 2) void gemm_kernel(const unsigned short* __restrict__ A,
                                                      const unsigned short* __restrict__ Bt,
                                                      unsigned short* __restrict__ U) {
  __shared__ alignas(16) unsigned short As[4][BM * BKC];  // 64 KB
  __shared__ alignas(16) unsigned short Bs[4][BN * BKC];  // 64 KB
  const int tid  = threadIdx.x;
  const int wave = tid >> 6, lane = tid & 63;
  const int quad = lane >> 4, lrow = lane & 15;
  const int wm = (wave >> 2) * 128;  // 2 M-waves
  const int wn = (wave & 3) * 64;    // 4 N-waves

  // XCD-rectangle swizzle: 768 blocks = 8 XCD x 3 rounds x 32 slots (4y x 8x)
  const int f    = blockIdx.y * (GN / BN) + blockIdx.x;
  const int xcd  = f & 7;
  const int slot = f >> 3;
  const int rnd  = slot >> 5;        // 0..2
  const int ss   = slot & 31;        // 0..31
  const int mBase = (4 * xcd + (ss & 3)) * BM;   // y-tile 0..31
  const int nBase = (8 * rnd + (ss >> 2)) * BN;  // x-tile 0..23

  floatx4 acc[8][4] = {};

  // staging: thread owns 16B slots L0=tid, L1=tid+512 of each slice (lane-linear
  // LDS dest). Invert swizzle to find the (row, k-slot) this slot must hold.
  const int L0 = tid, L1 = tid + 512;
  int r0, s0, r1, s1;
  { const int p = L0 >> 3, w = L0 & 7, v = w ^ (p & 7); r0 = 2 * p + (v >> 2); s0 = v & 3; }
  { const int p = L1 >> 3, w = L1 & 7, v = w ^ (p & 7); r1 = 2 * p + (v >> 2); s1 = v & 3; }
  const unsigned short* aG0 = A  + (size_t)(mBase + r0) * GK + s0 * 8;
  const unsigned short* aG1 = A  + (size_t)(mBase + r1) * GK + s1 * 8;
  const unsigned short* bG0 = Bt + (size_t)(nBase + r0) * GK + s0 * 8;
  const unsigned short* bG1 = Bt + (size_t)(nBase + r1) * GK + s1 * 8;

  // ds_read byte offsets within a slice (+16 rows = +1024 B)
  const int rA = wm + lrow;
  const int SA0 = (rA >> 1) * 128 + ((((rA & 1) * 4 + quad) ^ ((rA >> 1) & 7)) * 16);
  const int rB = wn + lrow;
  const int SB0 = (rB >> 1) * 128 + ((((rB & 1) * 4 + quad) ^ ((rB >> 1) & 7)) * 16);
  const char* AsB = (const char*)As;
  const char* BsB = (const char*)Bs;
  char* AsL = (char*)As;
  char* BsL = (char*)Bs;

  // prologue: stage chunks 0,1,2 (12 loads/thread in flight)
#pragma unroll
  for (int c = 0; c < 3; ++c) {
    unsigned short* ad = (unsigned short*)(AsL + c * 16384);
    unsigned short* bd = (unsigned short*)(BsL + c * 16384);
    async16(aG0 + c * BKC, ad + L0 * 8);
    async16(aG1 + c * BKC, ad + L1 * 8);
    async16(bG0 + c * BKC, bd + L0 * 8);
    async16(bG1 + c * BKC, bd + L1 * 8);
  }

  // main loop: chunks 0..59 (stage c+3), then peeled 60..63
#pragma unroll 1
  for (int cc = 0; cc < 15; ++cc) {
    const int cb = cc * 4;
#pragma unroll
    for (int j = 0; j < 4; ++j) {
      WAITV(8);
      CHUNK(cb + j, j, true);
    }
  }
  WAITV(8); CHUNK(60, 0, true);   // stages chunk 63
  WAITV(8); CHUNK(61, 1, false);
  WAITV(4); CHUNK(62, 2, false);
  WAITV(0); CHUNK(63, 3, false);

  // C/D layout: col = lane&15 (N), row = quad*4 + reg (M). Flat U: col = gn.
#pragma unroll
  for (int mt = 0; mt < 8; ++mt) {
    const int gm = mBase + wm + mt * 16 + quad * 4;
#pragma unroll
    for (int nt = 0; nt < 4; ++nt) {
      const int gn = nBase + wn + nt * 16 + lrow;
#pragma unroll
      for (int q = 0; q < 4; ++q)
        U[(size_t)(gm + q) * GN + gn] = f2bf(acc[mt][nt][q]);
    }
  }
}

// ---------------- SRU scan (flat layout: u0 plane, u1u2 interleaved, x in A_bf) -
// U row gm: [u0: d=0..2047][u1u2 interleaved: cols 2048+2d, 2048+2d+1].
// Rotating raw-register prefetch depth 16 (48 outstanding loads).
// This round: h-stores batched 8-at-a-time (keeps the in-order vm queue as
// clean load-runs; load->use distance <= 50 ops < 63 cap) and nontemporal
// (h is write-once 64 MB; don't evict the U lines we're about to read).
__global__ __launch_bounds__(64) void sru_scan_flat(const unsigned short* __restrict__ U,
                                                    const unsigned short* __restrict__ xbf,
                                                    const float* __restrict__ c0,
                                                    const float* __restrict__ wc,
                                                    const float* __restrict__ bias,
                                                    float* __restrict__ out) {
  const int e = blockIdx.x * 64 + threadIdx.x;
  const int b = e >> 11, d = e & (DIM - 1);
  const float vf = wc[d], vr = wc[DIM + d];
  const float bfv = bias[d], brv = bias[DIM + d];
  float c = c0[e];

  constexpr int PF = SCAN_PF;
  constexpr int US = BATCH * GN;
  constexpr int XS = BATCH * DIM;

  const unsigned short* u0p  = U + (size_t)b * GN + d;
  const unsigned short* u12p = U + (size_t)b * GN + DIM + 2 * d;
  const unsigned short* xp   = xbf + (size_t)b * DIM + d;
  float* hp = out + (size_t)b * DIM + d;

  unsigned pu0[PF], pu12[PF], pux[PF];
#pragma unroll
  for (int j = 0; j < PF; ++j) {
    pu0[j]  = u0p[(size_t)j * US];
    pu12[j] = *(const unsigned*)(u12p + (size_t)j * US);
    pux[j]  = xp[(size_t)j * XS];
  }
  const unsigned short* uf0  = u0p + (size_t)PF * US;
  const unsigned short* uf12 = u12p + (size_t)PF * US;
  const unsigned short* xf   = xp + (size_t)PF * XS;

  float hreg[8];
  for (int l0 = 0; l0 < L_SEQ; l0 += PF) {
#pragma unroll
    for (int j = 0; j < PF; ++j) {
      const unsigned r0 = pu0[j], r12 = pu12[j], rx = pux[j];
      pu0[j]  = uf0[0];
      pu12[j] = *(const unsigned*)uf12;
      pux[j]  = xf[0];
      uf0 += US; uf12 += US; xf += XS;
      const float a0 = __uint_as_float(r0 << 16);
      const float u1 = __uint_as_float(r12 << 16);
      const float u2 = __uint_as_float(r12 & 0xFFFF0000u);
      const float ax = __uint_as_float(rx << 16) * SCALE_X;
      const float f = sigmoidf_fast(u1 + fmaf(vf, c, bfv));
      c = fmaf(c - a0, f, a0);
      const float rr = sigmoidf_fast(u2 + fmaf(vr, c, brv));
      hreg[j & 7] = fmaf(rr, c - ax, ax);
      if ((j & 7) == 7) {
#pragma unroll
        for (int q = 0; q < 8; ++q) {
          __builtin_nontemporal_store(hreg[q], hp);
          hp += XS;
        }
      }
    }
  }
  out[(size_t)L_SEQ * XS + e] = c;
}

// --------------------------------- launcher ------------------------------------
extern "C" void kernel_launch(void* const* d_in, const int* in_sizes, int n_in,
                              void* d_out, int out_size, void* d_ws, size_t ws_size,
                              hipStream_t stream) {
  const float* x    = (const float*)d_in[0];
  const float* c0   = (const float*)d_in[1];
  const float* W    = (const float*)d_in[2];
  const float* wc   = (const float*)d_in[3];
  const float* bias = (const float*)d_in[4];
  float* out = (float*)d_out;

  char* ws = (char*)d_ws;
  // flat layout: A 33,554,432 (+512K scan-overread pad) | Bt 25,165,824 |
  //              U 100,663,296 (+2M scan-overread pad)
  unsigned short* A_bf  = (unsigned short*)(ws);
  unsigned short* Bt_bf = (unsigned short*)(ws + 34078720);
  unsigned short* U_bf  = (unsigned short*)(ws + 59244544);

  prep_kernel<<<7168, 256, 0, stream>>>((const float4*)x, A_bf, W, Bt_bf);
  gemm_kernel<<<dim3(GN / BN, GM / BM), 512, 0, stream>>>(A_bf, Bt_bf, U_bf);
  sru_scan_flat<<<256, 64, 0, stream>>>(U_bf, A_bf, c0, wc, bias, out);
}

// Round 10
// 397.020 us; speedup vs baseline: 1.2460x; 1.0754x over previous
//
#include <hip/hip_runtime.h>
#include <stdint.h>

// Problem constants (fixed by reference: L=1024, B=8, D=2048)
#define L_SEQ 1024
#define BATCH 8
#define DIM   2048
#define GM    8192   // L*B
#define GN    6144   // 3*D
#define GK    2048   // D
#define SCALE_X 1.7320508075688772f  // sqrt(1 + 2*exp(0))

// GEMM geometry: 256x256 tile, 8 waves (2M x 4N), k-ring of 4 slices of 32
#define BM 256
#define BN 256
#define BKC 32

using bf16x8  = __attribute__((ext_vector_type(8))) __bf16;
using floatx4 = __attribute__((ext_vector_type(4))) float;

__device__ __forceinline__ unsigned short f2bf(float f) {
  unsigned u = __float_as_uint(f);
  u += 0x7FFFu + ((u >> 16) & 1u);   // round-to-nearest-even
  return (unsigned short)(u >> 16);
}
__device__ __forceinline__ float sigmoidf_fast(float z) {
  return __builtin_amdgcn_rcpf(1.0f + __expf(-z));
}
__device__ __forceinline__ void async16(const unsigned short* g, unsigned short* l) {
  __builtin_amdgcn_global_load_lds(
      (__attribute__((address_space(1))) unsigned int*)g,
      (__attribute__((address_space(3))) unsigned int*)l,
      16, 0, 0);
}

// ------------- fused prep: transpose-cast W -> Bt  +  cast x -> A (bf16) --------
// Blocks [0, 3072): 64x64 transpose tiles (n-tile = blk%96, k-tile = blk/96).
//   Reads W via float4 (16B/lane); writes Bt rows as 8x 16B ushort8 chunks ->
//   each 8-thread group covers one full 128-B line (no partial-line RMW).
// Blocks [3072, 7168): grid-stride streaming cast of x.
// W col n = 3d+j -> j==0: Bt row d (u0 plane); j>0: Bt row DIM + 2d + (j-1).
__global__ __launch_bounds__(256) void prep_kernel(const float4* __restrict__ xin,
                                                   unsigned short* __restrict__ Aout,
                                                   const float* __restrict__ W,
                                                   unsigned short* __restrict__ Bt) {
  __shared__ float tile[64][65];
  const int blk = blockIdx.x;
  if (blk < 3072) {
    const int tx = threadIdx.x & 15, ty = threadIdx.x >> 4;
    const int n0 = (blk % 96) * 64;
    const int k0 = (blk / 96) * 64;
#pragma unroll
    for (int p = 0; p < 4; ++p) {
      const float4 v = *(const float4*)&W[(size_t)(k0 + ty + 16 * p) * GN + n0 + tx * 4];
      float* t = &tile[ty + 16 * p][tx * 4];
      t[0] = v.x; t[1] = v.y; t[2] = v.z; t[3] = v.w;
    }
    __syncthreads();
#pragma unroll
    for (int p = 0; p < 2; ++p) {
      const int jl = (threadIdx.x >> 3) + 32 * p;          // 0..63 n-local
      const int n = n0 + jl;
      const int dq = n / 3, j3 = n - 3 * dq;
      const int np = (j3 == 0) ? dq : (DIM + 2 * dq + (j3 - 1));
      const int klb = (threadIdx.x & 7) * 8;               // 0..56 k-local
      union { unsigned short s[8]; uint4 q; } o;
#pragma unroll
      for (int kk = 0; kk < 8; ++kk) o.s[kk] = f2bf(tile[klb + kk][jl]);
      *(uint4*)&Bt[(size_t)np * GK + k0 + klb] = o.q;
    }
  } else {
    const int n4 = (GM * GK) / 4;
    for (int i = (blk - 3072) * 256 + threadIdx.x; i < n4; i += 4096 * 256) {
      float4 v = xin[i];
      union { unsigned short s[4]; unsigned long long ll; } o;
      o.s[0] = f2bf(v.x); o.s[1] = f2bf(v.y); o.s[2] = f2bf(v.z); o.s[3] = f2bf(v.w);
      *(unsigned long long*)&Aout[(size_t)i * 4] = o.ll;
    }
  }
}

// ---------------- GEMM: U = A(GM x GK) * Bt(GN x GK)^T, bf16 out ----------------
// Round-4/8 structure verbatim (best measured: 197-200us, MfmaUtil 46, conf 0):
// 256x256 tile, 8 waves (2M x 4N), per-wave 128x64 = 8x4 reps of 16x16x32 MFMA.
// LDS = ring of 4 k-slices (k=32) per matrix: 128 KB, 1 blk/CU.
// Per chunk c: WAITV(8) ; BAR0 ; R0(8 ds_read) + stageA(c+3) ; BAR1 ; lgkm0 ;
// 16 MFMA ; BAR2 ; R1(4 ds_read) + stageB(c+3) ; BAR3 ; lgkm0 ; 16 MFMA.
// WAITV(8) waits only chunk c's loads (issued 3 chunks earlier -> free).
// LDS swizzle: 16B slot S(row,s) = (row>>1)*8 + (((row&1)*4+s)^((row>>1)&7));
// read-side XOR + inverse-permuted global source (LDS dest lane-linear).
// XCD-rectangle swizzle: 768 = 8 XCD x 3 rounds x (4y x 8x).

#define WAITV(N) asm volatile("s_waitcnt vmcnt(" #N ")" ::: "memory")
#define LGKM0 asm volatile("s_waitcnt lgkmcnt(0)" ::: "memory"); \
              __builtin_amdgcn_sched_barrier(0)

#define CHUNK(cexpr, SL, DOSTAGE)                                             \
  {                                                                           \
    __builtin_amdgcn_s_barrier();  /* BAR0 */                                 \
    __builtin_amdgcn_sched_barrier(0);                                        \
    const int c_ = (cexpr);                                                   \
    const char* aB_ = AsB + (SL) * 16384;                                     \
    const char* bB_ = BsB + (SL) * 16384;                                     \
    bf16x8 bF[4], aF[4];                                                      \
    _Pragma("unroll") for (int nt = 0; nt < 4; ++nt)                          \
        bF[nt] = *(const bf16x8*)(bB_ + SB0 + nt * 1024);                     \
    _Pragma("unroll") for (int mt = 0; mt < 4; ++mt)                          \
        aF[mt] = *(const bf16x8*)(aB_ + SA0 + mt * 1024);                     \
    if (DOSTAGE) {                                                            \
      unsigned short* ad_ = (unsigned short*)(AsL + ((c_ + 3) & 3) * 16384);  \
      const int ko_ = (c_ + 3) * BKC;                                         \
      async16(aG0 + ko_, ad_ + L0 * 8);                                       \
      async16(aG1 + ko_, ad_ + L1 * 8);                                       \
    }                                                                         \
    __builtin_amdgcn_sched_barrier(0);                                        \
    __builtin_amdgcn_s_barrier();  /* BAR1: read-burst | MFMA-burst fence */  \
    LGKM0;                                                                    \
    __builtin_amdgcn_s_setprio(1);                                            \
    _Pragma("unroll") for (int mt = 0; mt < 4; ++mt)                          \
      _Pragma("unroll") for (int nt = 0; nt < 4; ++nt)                        \
        acc[mt][nt] = __builtin_amdgcn_mfma_f32_16x16x32_bf16(                \
            aF[mt], bF[nt], acc[mt][nt], 0, 0, 0);                            \
    __builtin_amdgcn_s_setprio(0);                                            \
    __builtin_amdgcn_sched_barrier(0);                                        \
    __builtin_amdgcn_s_barrier();  /* BAR2 */                                 \
    _Pragma("unroll") for (int mt = 0; mt < 4; ++mt)                          \
        aF[mt] = *(const bf16x8*)(aB_ + SA0 + 4096 + mt * 1024);              \
    if (DOSTAGE) {                                                            \
      unsigned short* bd_ = (unsigned short*)(BsL + ((c_ + 3) & 3) * 16384);  \
      const int ko_ = (c_ + 3) * BKC;                                         \
      async16(bG0 + ko_, bd_ + L0 * 8);                                       \
      async16(bG1 + ko_, bd_ + L1 * 8);                                       \
    }                                                                         \
    __builtin_amdgcn_sched_barrier(0);                                        \
    __builtin_amdgcn_s_barrier();  /* BAR3 */                                 \
    LGKM0;                                                                    \
    __builtin_amdgcn_s_setprio(1);                                            \
    _Pragma("unroll") for (int mt = 0; mt < 4; ++mt)                          \
      _Pragma("unroll") for (int nt = 0; nt < 4; ++nt)                        \
        acc[mt + 4][nt] = __builtin_amdgcn_mfma_f32_16x16x32_bf16(            \
            aF[mt], bF[nt], acc[mt + 4][nt], 0, 0, 0);                        \
    __builtin_amdgcn_s_setprio(0);                                            \
    __builtin_amdgcn_sched_barrier(0);                                        \
  }

__global__ __launch_bounds__(512, 2) void gemm_kernel(const unsigned short* __restrict__ A,
                                                      const unsigned short* __restrict__ Bt,
                                                      unsigned short* __restrict__ U) {
  __shared__ alignas(16) unsigned short As[4][BM * BKC];  // 64 KB
  __shared__ alignas(16) unsigned short Bs[4][BN * BKC];  // 64 KB
  const int tid  = threadIdx.x;
  const int wave = tid >> 6, lane = tid & 63;
  const int quad = lane >> 4, lrow = lane & 15;
  const int wm = (wave >> 2) * 128;  // 2 M-waves
  const int wn = (wave & 3) * 64;    // 4 N-waves

  // XCD-rectangle swizzle: 768 blocks = 8 XCD x 3 rounds x 32 slots (4y x 8x)
  const int f    = blockIdx.y * (GN / BN) + blockIdx.x;
  const int xcd  = f & 7;
  const int slot = f >> 3;
  const int rnd  = slot >> 5;        // 0..2
  const int ss   = slot & 31;        // 0..31
  const int mBase = (4 * xcd + (ss & 3)) * BM;   // y-tile 0..31
  const int nBase = (8 * rnd + (ss >> 2)) * BN;  // x-tile 0..23

  floatx4 acc[8][4] = {};

  // staging: thread owns 16B slots L0=tid, L1=tid+512 of each slice (lane-linear
  // LDS dest). Invert swizzle to find the (row, k-slot) this slot must hold.
  const int L0 = tid, L1 = tid + 512;
  int r0, s0, r1, s1;
  { const int p = L0 >> 3, w = L0 & 7, v = w ^ (p & 7); r0 = 2 * p + (v >> 2); s0 = v & 3; }
  { const int p = L1 >> 3, w = L1 & 7, v = w ^ (p & 7); r1 = 2 * p + (v >> 2); s1 = v & 3; }
  const unsigned short* aG0 = A  + (size_t)(mBase + r0) * GK + s0 * 8;
  const unsigned short* aG1 = A  + (size_t)(mBase + r1) * GK + s1 * 8;
  const unsigned short* bG0 = Bt + (size_t)(nBase + r0) * GK + s0 * 8;
  const unsigned short* bG1 = Bt + (size_t)(nBase + r1) * GK + s1 * 8;

  // ds_read byte offsets within a slice (+16 rows = +1024 B)
  const int rA = wm + lrow;
  const int SA0 = (rA >> 1) * 128 + ((((rA & 1) * 4 + quad) ^ ((rA >> 1) & 7)) * 16);
  const int rB = wn + lrow;
  const int SB0 = (rB >> 1) * 128 + ((((rB & 1) * 4 + quad) ^ ((rB >> 1) & 7)) * 16);
  const char* AsB = (const char*)As;
  const char* BsB = (const char*)Bs;
  char* AsL = (char*)As;
  char* BsL = (char*)Bs;

  // prologue: stage chunks 0,1,2 (12 loads/thread in flight)
#pragma unroll
  for (int c = 0; c < 3; ++c) {
    unsigned short* ad = (unsigned short*)(AsL + c * 16384);
    unsigned short* bd = (unsigned short*)(BsL + c * 16384);
    async16(aG0 + c * BKC, ad + L0 * 8);
    async16(aG1 + c * BKC, ad + L1 * 8);
    async16(bG0 + c * BKC, bd + L0 * 8);
    async16(bG1 + c * BKC, bd + L1 * 8);
  }

  // main loop: chunks 0..59 (stage c+3), then peeled 60..63
#pragma unroll 1
  for (int cc = 0; cc < 15; ++cc) {
    const int cb = cc * 4;
#pragma unroll
    for (int j = 0; j < 4; ++j) {
      WAITV(8);
      CHUNK(cb + j, j, true);
    }
  }
  WAITV(8); CHUNK(60, 0, true);   // stages chunk 63
  WAITV(8); CHUNK(61, 1, false);
  WAITV(4); CHUNK(62, 2, false);
  WAITV(0); CHUNK(63, 3, false);

  // C/D layout: col = lane&15 (N), row = quad*4 + reg (M). Flat U: col = gn.
#pragma unroll
  for (int mt = 0; mt < 8; ++mt) {
    const int gm = mBase + wm + mt * 16 + quad * 4;
#pragma unroll
    for (int nt = 0; nt < 4; ++nt) {
      const int gn = nBase + wn + nt * 16 + lrow;
#pragma unroll
      for (int q = 0; q < 4; ++q)
        U[(size_t)(gm + q) * GN + gn] = f2bf(acc[mt][nt][q]);
    }
  }
}

// ------------- SRU scan: producer/consumer wave split over an LDS ring ----------
// 256 blocks x 128 threads. Block (b,dch) owns 64 columns d = dch*64 + lane.
// Wave 1 (producer): stages the block's 3 streams (u0, u1u2, x) for 16-step
// slots into a 4-slot LDS ring via 8x global_load_lds dwordx4 per slot, each
// instruction moving 1 KB with per-lane gather addresses (steps x 16B chunks).
// Steady state: 24 instructions = 24 KB in flight (vs 8 KB for the old
// single-wave scalar prefetch -> 3x MLP). WAITV(16) seals slot p+1 before the
// phase barrier; slot p+3 overwrites slot p-1, whose consumer reads completed
// before the phase-p barrier. Tail: WAITV 8/0. One s_barrier per 16 steps.
// Wave 0 (consumer): per step 3 short LDS reads (<=2-way banks, free), the
// recurrence math (identical ops/order -> bit-identical), nontemporal h-store.
__global__ __launch_bounds__(128) void sru_scan_pc(const unsigned short* __restrict__ U,
                                                   const unsigned short* __restrict__ xbf,
                                                   const float* __restrict__ c0,
                                                   const float* __restrict__ wc,
                                                   const float* __restrict__ bias,
                                                   float* __restrict__ out) {
  __shared__ alignas(16) unsigned short Sm[4][4096];  // 4 slots x 8 KB
  const int tid  = threadIdx.x;
  const int wave = tid >> 6, lane = tid & 63;
  const int blk = blockIdx.x;
  const int b = blk >> 5, dch = blk & 31;
  const int d0 = dch * 64;

  constexpr size_t US  = (size_t)BATCH * GN;   // shorts per l-step (U)
  constexpr size_t XSs = (size_t)BATCH * DIM;  // shorts per l-step (x)
  constexpr int XS = BATCH * DIM;              // floats per l-step (out)

  if (wave == 1) {
    // ---------------- producer ----------------
    const int s8 = lane >> 3, c8 = lane & 7;    // 8-step groups (u0, x)
    const int s4 = lane >> 4, c16 = lane & 15;  // 4-step groups (u1u2)
    const unsigned short* u0g  = U   + (size_t)b * GN + d0 + c8 * 8 + (size_t)s8 * US;
    const unsigned short* u12g = U   + (size_t)b * GN + DIM + 2 * d0 + c16 * 8 + (size_t)s4 * US;
    const unsigned short* xg   = xbf + (size_t)b * DIM + d0 + c8 * 8 + (size_t)s8 * XSs;

#define STAGE_SLOT(SL, L0S)                                                   \
    {                                                                         \
      unsigned short* dst = &Sm[(SL)][0] + lane * 8;                          \
      const size_t l0_ = (size_t)(L0S);                                       \
      async16(u0g + l0_ * US, dst);              /* steps l0..l0+7   */       \
      async16(u0g + (l0_ + 8) * US, dst + 512);  /* steps l0+8..+15  */       \
      async16(u12g + l0_ * US, dst + 1024);      /* steps l0..l0+3   */       \
      async16(u12g + (l0_ + 4) * US, dst + 1536);                             \
      async16(u12g + (l0_ + 8) * US, dst + 2048);                             \
      async16(u12g + (l0_ + 12) * US, dst + 2560);                            \
      async16(xg + l0_ * XSs, dst + 3072);                                    \
      async16(xg + (l0_ + 8) * XSs, dst + 3584);                              \
    }

    // prologue: slots 0,1,2 (24 in flight); seal slot 0
    STAGE_SLOT(0, 0); STAGE_SLOT(1, 16); STAGE_SLOT(2, 32);
    WAITV(16);
#pragma unroll 1
    for (int p = 0; p < 64; ++p) {
      __builtin_amdgcn_s_barrier();
      __builtin_amdgcn_sched_barrier(0);
      if (p < 61) {
        STAGE_SLOT((p + 3) & 3, 16 * (p + 3));
        WAITV(16);           // seal slot p+1; keep p+2, p+3 in flight
      } else if (p == 61) {
        WAITV(8);            // seal slot 62
      } else if (p == 62) {
        WAITV(0);            // seal slot 63
      }
      __builtin_amdgcn_sched_barrier(0);
    }
#undef STAGE_SLOT
  } else {
    // ---------------- consumer ----------------
    const int d = d0 + lane;
    const int e = b * DIM + d;
    const float vf = wc[d], vr = wc[DIM + d];
    const float bfv = bias[d], brv = bias[DIM + d];
    float c = c0[e];
    float* hp = out + (size_t)b * DIM + d;

#pragma unroll 1
    for (int p = 0; p < 64; ++p) {
      __builtin_amdgcn_s_barrier();
      __builtin_amdgcn_sched_barrier(0);
      const unsigned short* sp = &Sm[p & 3][0];
#pragma unroll
      for (int s = 0; s < 16; ++s) {
        const unsigned u0v = sp[s * 64 + lane];
        const unsigned r12 = *(const unsigned*)&sp[1024 + s * 128 + lane * 2];
        const unsigned xv  = sp[3072 + s * 64 + lane];
        const float a0 = __uint_as_float(u0v << 16);
        const float u1 = __uint_as_float(r12 << 16);
        const float u2 = __uint_as_float(r12 & 0xFFFF0000u);
        const float ax = __uint_as_float(xv << 16) * SCALE_X;
        const float fg = sigmoidf_fast(u1 + fmaf(vf, c, bfv));
        c = fmaf(c - a0, fg, a0);
        const float rr = sigmoidf_fast(u2 + fmaf(vr, c, brv));
        __builtin_nontemporal_store(fmaf(rr, c - ax, ax), hp);
        hp += XS;
      }
      LGKM0;  // all slot reads complete before passing the next barrier
    }
    out[(size_t)L_SEQ * XS + e] = c;
  }
}

// --------------------------------- launcher ------------------------------------
extern "C" void kernel_launch(void* const* d_in, const int* in_sizes, int n_in,
                              void* d_out, int out_size, void* d_ws, size_t ws_size,
                              hipStream_t stream) {
  const float* x    = (const float*)d_in[0];
  const float* c0   = (const float*)d_in[1];
  const float* W    = (const float*)d_in[2];
  const float* wc   = (const float*)d_in[3];
  const float* bias = (const float*)d_in[4];
  float* out = (float*)d_out;

  char* ws = (char*)d_ws;
  // flat layout: A 33,554,432 (+512K pad) | Bt 25,165,824 | U 100,663,296 (+pad)
  unsigned short* A_bf  = (unsigned short*)(ws);
  unsigned short* Bt_bf = (unsigned short*)(ws + 34078720);
  unsigned short* U_bf  = (unsigned short*)(ws + 59244544);

  prep_kernel<<<7168, 256, 0, stream>>>((const float4*)x, A_bf, W, Bt_bf);
  gemm_kernel<<<dim3(GN / BN, GM / BM), 512, 0, stream>>>(A_bf, Bt_bf, U_bf);
  sru_scan_pc<<<256, 128, 0, stream>>>(U_bf, A_bf, c0, wc, bias, out);
}